// Round 3
// baseline (213.212 us; speedup 1.0000x reference)
//
#include <hip/hip_runtime.h>

// Problem constants (from reference)
#define NPIX   786432      // C*H*W = 3*512*512
#define NSP    55050       // noise pixels per sample
#define BATCH  64
#define MASK_WORDS_PER_SAMPLE (NPIX / 16)                   // 49152 u32 (2 bits/pixel)
#define MASK_WORDS_TOTAL      (MASK_WORDS_PER_SAMPLE * BATCH) // 3,145,728 u32
#define MASK_BYTES_TOTAL      ((size_t)MASK_WORDS_TOTAL * 4)  // 12,582,912 B

typedef float f32x4 __attribute__((ext_vector_type(4)));
typedef unsigned int  u32;
typedef unsigned char u8;

// ---- path A: mask-fused (3 kernels, one streaming pass over the image) ----

__global__ __launch_bounds__(256) void zero_mask_kernel(f32x4* __restrict__ ws, int n4) {
    int stride = gridDim.x * blockDim.x;
    f32x4 z = {0.f, 0.f, 0.f, 0.f};
    for (int i = blockIdx.x * blockDim.x + threadIdx.x; i < n4; i += stride)
        ws[i] = z;
}

// Scatter 2-bit codes: bit(2k)=noise flag, bit(2k+1)=salt value for pixel k of
// the 16-pixel word. Pixels are unique per sample (randperm prefix), so all
// OR'd bit-pairs are disjoint -> deterministic regardless of atomic order.
__global__ __launch_bounds__(256) void scatter_mask_kernel(
    const int* __restrict__ indices, const int* __restrict__ num_salt,
    u32* __restrict__ mask) {
    int b = blockIdx.y;
    int j = blockIdx.x * blockDim.x + threadIdx.x;
    if (j >= NSP) return;
    int p = indices[b * NSP + j];                 // coalesced
    u32 salt = (j < num_salt[b]) ? 1u : 0u;
    u32 bits = (1u | (salt << 1)) << ((p & 15) * 2);
    atomicOr(mask + b * MASK_WORDS_PER_SAMPLE + (p >> 4), bits);  // L3-resident
}

// One streaming pass: mask byte i covers exactly float4 i (4 pixels x 2 bits).
// NT loads (input read once) + NT stores (output never re-read on device)
// keep the 256 MB L3 free for the mask + indices.
__global__ __launch_bounds__(256) void fused_kernel(
    const f32x4* __restrict__ in, f32x4* __restrict__ out,
    const u8* __restrict__ mask, int n4) {
    int stride = gridDim.x * blockDim.x;
    for (int i = blockIdx.x * blockDim.x + threadIdx.x; i < n4; i += stride) {
        f32x4 v = __builtin_nontemporal_load(in + i);
        u8 m = mask[i];                            // coalesced 1 B/lane, cache-hot
        f32x4 o;
        o.x = (m & 1u)        ? (float)((m >> 1) & 1u) : fminf(fmaxf(v.x, 0.f), 1.f);
        o.y = ((m >> 2) & 1u) ? (float)((m >> 3) & 1u) : fminf(fmaxf(v.y, 0.f), 1.f);
        o.z = ((m >> 4) & 1u) ? (float)((m >> 5) & 1u) : fminf(fmaxf(v.z, 0.f), 1.f);
        o.w = ((m >> 6) & 1u) ? (float)((m >> 7) & 1u) : fminf(fmaxf(v.w, 0.f), 1.f);
        __builtin_nontemporal_store(o, out + i);
    }
}

// ---- path B fallback (ws too small): original two-pass ----

__global__ __launch_bounds__(256) void copy_clip_kernel(
    const f32x4* __restrict__ in, f32x4* __restrict__ out, int n4) {
    int stride = gridDim.x * blockDim.x;
    for (int i = blockIdx.x * blockDim.x + threadIdx.x; i < n4; i += stride) {
        f32x4 v = __builtin_nontemporal_load(in + i);
        v.x = fminf(fmaxf(v.x, 0.f), 1.f);
        v.y = fminf(fmaxf(v.y, 0.f), 1.f);
        v.z = fminf(fmaxf(v.z, 0.f), 1.f);
        v.w = fminf(fmaxf(v.w, 0.f), 1.f);
        out[i] = v;
    }
}

__global__ __launch_bounds__(256) void scatter_kernel(
    const int* __restrict__ indices, const int* __restrict__ num_salt,
    float* __restrict__ out) {
    int b = blockIdx.y;
    int j = blockIdx.x * blockDim.x + threadIdx.x;
    if (j >= NSP) return;
    int idx = indices[b * NSP + j];
    out[(size_t)b * NPIX + idx] = (j < num_salt[b]) ? 1.0f : 0.0f;
}

extern "C" void kernel_launch(void* const* d_in, const int* in_sizes, int n_in,
                              void* d_out, int out_size, void* d_ws, size_t ws_size,
                              hipStream_t stream) {
    const float* x        = (const float*)d_in[0];
    const int*   indices  = (const int*)d_in[1];
    const int*   num_salt = (const int*)d_in[2];
    float*       out      = (float*)d_out;
    int n4 = out_size / 4;                        // 12,582,912 float4s

    if (ws_size >= MASK_BYTES_TOTAL) {
        u32* mask = (u32*)d_ws;
        // (a) zero the 12.6 MB mask
        zero_mask_kernel<<<2048, 256, 0, stream>>>((f32x4*)d_ws, MASK_WORDS_TOTAL / 4);
        // (b) scatter noise codes into the mask (L3-resident atomics)
        dim3 sgrid((NSP + 255) / 256, BATCH);
        scatter_mask_kernel<<<sgrid, 256, 0, stream>>>(indices, num_salt, mask);
        // (c) single fused streaming pass
        fused_kernel<<<4096, 256, 0, stream>>>(
            (const f32x4*)x, (f32x4*)out, (const u8*)d_ws, n4);
    } else {
        copy_clip_kernel<<<2048, 256, 0, stream>>>((const f32x4*)x, (f32x4*)out, n4);
        dim3 sgrid((NSP + 255) / 256, BATCH);
        scatter_kernel<<<sgrid, 256, 0, stream>>>(indices, num_salt, out);
    }
}

// Round 4
// 114.605 us; speedup vs baseline: 1.8604x; 1.8604x over previous
//
#include <hip/hip_runtime.h>

// Problem constants (from reference)
#define NPIX   786432      // C*H*W = 3*512*512
#define NSP    55050       // noise pixels per sample
#define BATCH  64

typedef float f32x4 __attribute__((ext_vector_type(4)));

// Kernel 1: streaming copy + clip, 4-way MLP per thread.
// NT loads: input is read once and must NOT evict the output from the 256 MB
// L3 (the scatter needs out L3-resident). Plain stores: keep out cached.
// n4 = 12,582,912 = 24 * (2048*256), so the 4-strided pattern fits exactly.
__global__ __launch_bounds__(256) void copy_clip_mlp(
    const f32x4* __restrict__ in, f32x4* __restrict__ out, int n4) {
    int S   = gridDim.x * blockDim.x;          // 524288
    int tid = blockIdx.x * blockDim.x + threadIdx.x;
    for (int base = tid; base < n4; base += 4 * S) {
        int i1 = base + S, i2 = base + 2 * S, i3 = base + 3 * S;
        // issue all loads first (4 outstanding NT loads per lane)
        f32x4 v0 = __builtin_nontemporal_load(in + base);
        f32x4 v1 = (i1 < n4) ? __builtin_nontemporal_load(in + i1) : v0;
        f32x4 v2 = (i2 < n4) ? __builtin_nontemporal_load(in + i2) : v0;
        f32x4 v3 = (i3 < n4) ? __builtin_nontemporal_load(in + i3) : v0;
        #define CLIP4(v) \
            v.x = fminf(fmaxf(v.x, 0.f), 1.f); v.y = fminf(fmaxf(v.y, 0.f), 1.f); \
            v.z = fminf(fmaxf(v.z, 0.f), 1.f); v.w = fminf(fmaxf(v.w, 0.f), 1.f);
        CLIP4(v0) CLIP4(v1) CLIP4(v2) CLIP4(v3)
        #undef CLIP4
        out[base] = v0;
        if (i1 < n4) out[i1] = v1;
        if (i2 < n4) out[i2] = v2;
        if (i3 < n4) out[i3] = v3;
    }
}

// Kernel 2: direct scatter, 8-way MLP per thread.
// Indices are per-sample randperm prefixes -> unique targets, plain stores,
// order-free. Load all 8 indices (coalesced), then 8 independent scattered
// stores (should dirty-hit L3 since out was just written with plain stores).
__global__ __launch_bounds__(256) void scatter_ilp(
    const int* __restrict__ indices, const int* __restrict__ num_salt,
    float* __restrict__ out) {
    int b  = blockIdx.y;
    int ns = num_salt[b];                      // uniform per block -> scalar
    const int* ind = indices + b * NSP;
    float* o = out + (size_t)b * NPIX;
    int base = blockIdx.x * 2048 + threadIdx.x;
    int idx[8];
    #pragma unroll
    for (int k = 0; k < 8; ++k) {
        int j = base + k * 256;
        idx[k] = (j < NSP) ? ind[j] : -1;      // coalesced index loads
    }
    #pragma unroll
    for (int k = 0; k < 8; ++k) {
        int j = base + k * 256;
        if (idx[k] >= 0) o[idx[k]] = (j < ns) ? 1.0f : 0.0f;
    }
}

extern "C" void kernel_launch(void* const* d_in, const int* in_sizes, int n_in,
                              void* d_out, int out_size, void* d_ws, size_t ws_size,
                              hipStream_t stream) {
    const float* x        = (const float*)d_in[0];
    const int*   indices  = (const int*)d_in[1];
    const int*   num_salt = (const int*)d_in[2];
    float*       out      = (float*)d_out;

    int n4 = out_size / 4;                     // 12,582,912 float4s
    copy_clip_mlp<<<2048, 256, 0, stream>>>((const f32x4*)x, (f32x4*)out, n4);

    dim3 sgrid((NSP + 2047) / 2048, BATCH);    // (27, 64)
    scatter_ilp<<<sgrid, 256, 0, stream>>>(indices, num_salt, out);
}